// Round 9
// baseline (345.658 us; speedup 1.0000x reference)
//
#include <hip/hip_runtime.h>
#include <hip/hip_bf16.h>

typedef __bf16 bf16_t;
typedef __attribute__((ext_vector_type(4))) __bf16 bf16x4;
typedef __attribute__((ext_vector_type(8))) __bf16 bf16x8;
typedef __attribute__((ext_vector_type(4))) float f32x4;

#define B_DIM 4
#define T_DIM 2048
#define C_DIM 1024
#define H_DIM 16
#define D_DIM 64
#define M_TOK (B_DIM * T_DIM)   /* 8192 */
#define N_QKV (3 * C_DIM)       /* 3072 */
#define NT    (T_DIM / 64)      /* 32 k/q tiles */
#define KSTR  72                /* padded LDS stride: read slot=(row+quad)&7, 2-way/phase */
#define CSC   0.18033688011112042f /* log2(e)/sqrt(64) */

__device__ __forceinline__ void gload_lds16(const bf16_t* g, bf16_t* l) {
  __builtin_amdgcn_global_load_lds((const __attribute__((address_space(1))) void*)(g),
                                   (__attribute__((address_space(3))) void*)(l), 16, 0, 0);
}

// ---------------- fp32 -> bf16 convert (vectorized) ----------------
// (bf16_t) casts, not manual packing (r5/r6 lesson).
__global__ void cvt_f32_to_bf16(const float* __restrict__ in, bf16_t* __restrict__ out, int n4) {
  int i = blockIdx.x * blockDim.x + threadIdx.x;
  if (i >= n4) return;
  float4 v = ((const float4*)in)[i];
  bf16x4 o;
  o[0] = (bf16_t)v.x; o[1] = (bf16_t)v.y; o[2] = (bf16_t)v.z; o[3] = (bf16_t)v.w;
  ((bf16x4*)out)[i] = o;
}

// ---------------- transpose [K][N] fp32 -> [N][K] bf16 ----------------
__global__ void transpose_f32_to_bf16(const float* __restrict__ in, bf16_t* __restrict__ out,
                                      int K, int N) {
  __shared__ float tile[32][33];
  int bx = blockIdx.x * 32;  // n
  int by = blockIdx.y * 32;  // k
  int tx = threadIdx.x, ty = threadIdx.y;
#pragma unroll
  for (int i = 0; i < 32; i += 8)
    tile[ty + i][tx] = in[(size_t)(by + ty + i) * N + bx + tx];
  __syncthreads();
#pragma unroll
  for (int i = 0; i < 32; i += 8)
    out[(size_t)(bx + ty + i) * K + by + tx] = (bf16_t)tile[tx][ty + i];
}

// ---------------- bf16 GEMM 128x128 (m97 structure): Cb = A * Bt^T + bias ----------------
#define BM 128
#define BN 128
#define BK 32

__global__ __launch_bounds__(256, 4)
void gemm_bt_bias(const bf16_t* __restrict__ A, const bf16_t* __restrict__ Bt,
                  const float* __restrict__ bias, bf16_t* __restrict__ Cb,
                  int M, int N, int K) {
  __shared__ alignas(16) bf16_t As[BM * BK];
  __shared__ alignas(16) bf16_t Bs[BN * BK];
  const int tid = threadIdx.x;
  const int lane = tid & 63;
  const int wave = tid >> 6;
  const int wr = (wave >> 1) * 64, wc = (wave & 1) * 64;
  const int quad = lane >> 4, l16 = lane & 15;
  const int row0 = blockIdx.x * BM, col0 = blockIdx.y * BN;

  const int srow = wave * 32 + (lane >> 2);
  const int scol = (lane & 3) * 8;
  const bf16_t* Ag = A + (size_t)(row0 + srow) * K + scol;
  const bf16_t* Bg = Bt + (size_t)(col0 + srow) * K + scol;
  bf16_t* AsW = &As[(wave * 32) * BK];
  bf16_t* BsW = &Bs[(wave * 32) * BK];

  f32x4 acc[4][4];
#pragma unroll
  for (int i = 0; i < 4; ++i)
#pragma unroll
    for (int j = 0; j < 4; ++j)
      acc[i][j] = (f32x4){0.f, 0.f, 0.f, 0.f};

  for (int k0 = 0; k0 < K; k0 += BK) {
    __syncthreads();
    gload_lds16(Ag + k0, AsW);
    gload_lds16(Ag + k0 + (size_t)16 * K, AsW + 16 * BK);
    gload_lds16(Bg + k0, BsW);
    gload_lds16(Bg + k0 + (size_t)16 * K, BsW + 16 * BK);
    __syncthreads();
    bf16x8 af[4], bfr[4];
#pragma unroll
    for (int i = 0; i < 4; ++i)
      af[i] = *(const bf16x8*)&As[(wr + i * 16 + l16) * BK + quad * 8];
#pragma unroll
    for (int j = 0; j < 4; ++j)
      bfr[j] = *(const bf16x8*)&Bs[(wc + j * 16 + l16) * BK + quad * 8];
#pragma unroll
    for (int i = 0; i < 4; ++i)
#pragma unroll
      for (int j = 0; j < 4; ++j)
        acc[i][j] = __builtin_amdgcn_mfma_f32_16x16x32_bf16(af[i], bfr[j], acc[i][j], 0, 0, 0);
  }

#pragma unroll
  for (int i = 0; i < 4; ++i)
#pragma unroll
    for (int j = 0; j < 4; ++j) {
      int col = col0 + wc + j * 16 + l16;
      float bv = bias[col];
#pragma unroll
      for (int r = 0; r < 4; ++r) {
        int row = row0 + wr + i * 16 + quad * 4 + r;
        Cb[(size_t)row * N + col] = (bf16_t)(acc[i][j][r] + bv);
      }
    }
}

// ---------------- bf16 GEMM 128x64, fp32 out (proj) ----------------
__global__ __launch_bounds__(256, 4)
void gemm_bt_bias_n64(const bf16_t* __restrict__ A, const bf16_t* __restrict__ Bt,
                      const float* __restrict__ bias, float* __restrict__ Cf,
                      int M, int N, int K) {
  __shared__ alignas(16) bf16_t As[BM * BK];
  __shared__ alignas(16) bf16_t Bs[64 * BK];
  const int tid = threadIdx.x;
  const int lane = tid & 63;
  const int wave = tid >> 6;
  const int wr = (wave >> 1) * 64, wc = (wave & 1) * 32;
  const int quad = lane >> 4, l16 = lane & 15;
  const int row0 = blockIdx.x * BM, col0 = blockIdx.y * 64;

  const int sr = lane >> 2;
  const int scol = (lane & 3) * 8;
  const bf16_t* Ag = A + (size_t)(row0 + wave * 32 + sr) * K + scol;
  const bf16_t* Bg = Bt + (size_t)(col0 + wave * 16 + sr) * K + scol;
  bf16_t* AsW = &As[(wave * 32) * BK];
  bf16_t* BsW = &Bs[(wave * 16) * BK];

  f32x4 acc[4][2];
#pragma unroll
  for (int i = 0; i < 4; ++i)
#pragma unroll
    for (int j = 0; j < 2; ++j)
      acc[i][j] = (f32x4){0.f, 0.f, 0.f, 0.f};

  for (int k0 = 0; k0 < K; k0 += BK) {
    __syncthreads();
    gload_lds16(Ag + k0, AsW);
    gload_lds16(Ag + k0 + (size_t)16 * K, AsW + 16 * BK);
    gload_lds16(Bg + k0, BsW);
    __syncthreads();
    bf16x8 af[4], bfr[2];
#pragma unroll
    for (int i = 0; i < 4; ++i)
      af[i] = *(const bf16x8*)&As[(wr + i * 16 + l16) * BK + quad * 8];
#pragma unroll
    for (int j = 0; j < 2; ++j)
      bfr[j] = *(const bf16x8*)&Bs[(wc + j * 16 + l16) * BK + quad * 8];
#pragma unroll
    for (int i = 0; i < 4; ++i)
#pragma unroll
      for (int j = 0; j < 2; ++j)
        acc[i][j] = __builtin_amdgcn_mfma_f32_16x16x32_bf16(af[i], bfr[j], acc[i][j], 0, 0, 0);
  }

#pragma unroll
  for (int i = 0; i < 4; ++i)
#pragma unroll
    for (int j = 0; j < 2; ++j) {
      int col = col0 + wc + j * 16 + l16;
      float bv = bias[col];
#pragma unroll
      for (int r = 0; r < 4; ++r) {
        int row = row0 + wr + i * 16 + quad * 4 + r;
        Cf[(size_t)row * N + col] = acc[i][j][r] + bv;
      }
    }
}

// ---------------- flash attention (causal), S^T orientation ----------------
// One q-tile per block, grid 2048, launch_bounds(256,4) (NOT 5 — r8's (256,5)
// coincided with post-timing divergence + slowdown; suspect register-cap
// side effects). All LDS accesses are __bf16-typed (bf16x4/bf16x8) so
// writes and reads share TBAA type — no reorder hazard.
__device__ __forceinline__ float exp_row_sum(f32x4 sv[4], bool diag, bf16_t* PsW,
                                             int l16, int quad, int wave) {
  if (diag) {
    const int qr = wave * 16 + l16;
#pragma unroll
    for (int ct = 0; ct < 4; ++ct)
#pragma unroll
      for (int r = 0; r < 4; ++r)
        if (ct * 16 + quad * 4 + r > qr) sv[ct][r] = -INFINITY;
  }
  float rsum = 0.f;
#pragma unroll
  for (int ct = 0; ct < 4; ++ct) {
    bf16x4 pk;
#pragma unroll
    for (int r = 0; r < 4; ++r) {
      float p = __builtin_amdgcn_exp2f(sv[ct][r] * CSC);
      rsum += p;
      pk[r] = (bf16_t)p;
    }
    *(bf16x4*)&PsW[l16 * KSTR + ct * 16 + quad * 4] = pk;
  }
  rsum += __shfl_xor(rsum, 16);
  rsum += __shfl_xor(rsum, 32);
  return rsum;
}

__global__ __launch_bounds__(256, 4)
void attn_fwd(const bf16_t* __restrict__ qkv, bf16_t* __restrict__ out) {
  __shared__ alignas(16) bf16_t Ks[64 * KSTR];         // [key][d]
  __shared__ alignas(16) bf16_t Vt[64 * KSTR];         // [d][key]
  __shared__ alignas(16) bf16_t Ps[4 * 16 * KSTR];     // per-wave [qrow][key]

  const int tid = threadIdx.x;
  const int lane = tid & 63;
  const int wave = tid >> 6;
  const int quad = lane >> 4, l16 = lane & 15;
  const int qt = NT - 1 - blockIdx.x;   // longest blocks first -> tail backfill
  const int h = blockIdx.y, b = blockIdx.z;
  const size_t tokBase = (size_t)b * T_DIM;

  const bf16_t* qp = qkv + (tokBase + qt * 64 + wave * 16 + l16) * N_QKV + h * D_DIM;
  bf16x8 q0 = *(const bf16x8*)(qp + quad * 8);
  bf16x8 q1 = *(const bf16x8*)(qp + 32 + quad * 8);

  f32x4 o_acc[4];
#pragma unroll
  for (int dt = 0; dt < 4; ++dt) o_acc[dt] = (f32x4){0.f, 0.f, 0.f, 0.f};
  float lsum = 0.f;

  const int tx = tid & 15, ty = tid >> 4;
  bf16_t* PsW = &Ps[wave * 16 * KSTR];
  const f32x4 zero4 = (f32x4){0.f, 0.f, 0.f, 0.f};

  // register prefetch of K/V tile 0 (bf16-typed)
  bf16x4 kreg[4], vreg[4];
  const bf16_t* kb0 = qkv + (tokBase + ty * 4) * N_QKV + h * D_DIM + C_DIM + tx * 4;
#pragma unroll
  for (int r = 0; r < 4; ++r) kreg[r] = *(const bf16x4*)(kb0 + (size_t)r * N_QKV);
#pragma unroll
  for (int r = 0; r < 4; ++r) vreg[r] = *(const bf16x4*)(kb0 + (size_t)r * N_QKV + C_DIM);

  for (int t = 0; t <= qt; ++t) {
    __syncthreads();
#pragma unroll
    for (int r = 0; r < 4; ++r)
      *(bf16x4*)&Ks[(ty * 4 + r) * KSTR + tx * 4] = kreg[r];
#pragma unroll
    for (int i = 0; i < 4; ++i) {
      bf16x4 p;
      p[0] = vreg[0][i]; p[1] = vreg[1][i]; p[2] = vreg[2][i]; p[3] = vreg[3][i];
      *(bf16x4*)&Vt[(tx * 4 + i) * KSTR + ty * 4] = p;
    }
    __syncthreads();
    if (t < qt) {
      const bf16_t* kb = qkv + (tokBase + (t + 1) * 64 + ty * 4) * N_QKV + h * D_DIM + C_DIM + tx * 4;
#pragma unroll
      for (int r = 0; r < 4; ++r) kreg[r] = *(const bf16x4*)(kb + (size_t)r * N_QKV);
#pragma unroll
      for (int r = 0; r < 4; ++r) vreg[r] = *(const bf16x4*)(kb + (size_t)r * N_QKV + C_DIM);
    }

    // S^T = K Q^T : lane holds col=l16 (qrow), rows quad*4+r (keys) per ct
    f32x4 sv[4];
#pragma unroll
    for (int ct = 0; ct < 4; ++ct) {
      bf16x8 kf0 = *(const bf16x8*)&Ks[(ct * 16 + l16) * KSTR + quad * 8];
      bf16x8 kf1 = *(const bf16x8*)&Ks[(ct * 16 + l16) * KSTR + 32 + quad * 8];
      sv[ct] = __builtin_amdgcn_mfma_f32_16x16x32_bf16(kf0, q0, zero4, 0, 0, 0);
      sv[ct] = __builtin_amdgcn_mfma_f32_16x16x32_bf16(kf1, q1, sv[ct], 0, 0, 0);
    }

    lsum += exp_row_sum(sv, t == qt, PsW, l16, quad, wave);
    bf16x8 p0 = *(const bf16x8*)&PsW[l16 * KSTR + quad * 8];
    bf16x8 p1 = *(const bf16x8*)&PsW[l16 * KSTR + 32 + quad * 8];

#pragma unroll
    for (int dt = 0; dt < 4; ++dt) {
      bf16x8 vf0 = *(const bf16x8*)&Vt[(dt * 16 + l16) * KSTR + quad * 8];
      bf16x8 vf1 = *(const bf16x8*)&Vt[(dt * 16 + l16) * KSTR + 32 + quad * 8];
      o_acc[dt] = __builtin_amdgcn_mfma_f32_16x16x32_bf16(vf0, p0, o_acc[dt], 0, 0, 0);
      o_acc[dt] = __builtin_amdgcn_mfma_f32_16x16x32_bf16(vf1, p1, o_acc[dt], 0, 0, 0);
    }
  }

  // ---- epilogue: lane holds qrow=l16, d = dt*16 + quad*4 + r
  float rl = 1.0f / lsum;
  bf16_t* op = out + (tokBase + qt * 64 + wave * 16 + l16) * C_DIM + h * D_DIM;
#pragma unroll
  for (int dt = 0; dt < 4; ++dt) {
    bf16x4 v;
    v[0] = (bf16_t)(o_acc[dt][0] * rl); v[1] = (bf16_t)(o_acc[dt][1] * rl);
    v[2] = (bf16_t)(o_acc[dt][2] * rl); v[3] = (bf16_t)(o_acc[dt][3] * rl);
    *(bf16x4*)(op + dt * 16 + quad * 4) = v;
  }
}

// ---------------- launcher ----------------
extern "C" void kernel_launch(void* const* d_in, const int* in_sizes, int n_in,
                              void* d_out, int out_size, void* d_ws, size_t ws_size,
                              hipStream_t stream) {
  const float* x      = (const float*)d_in[0];
  const float* W_attn = (const float*)d_in[1];
  const float* b_attn = (const float*)d_in[2];
  const float* W_proj = (const float*)d_in[3];
  const float* b_proj = (const float*)d_in[4];
  float* out = (float*)d_out;

  char* ws = (char*)d_ws;
  bf16_t* xb   = (bf16_t*)ws;  ws += (size_t)M_TOK * C_DIM * 2;
  bf16_t* Wat  = (bf16_t*)ws;  ws += (size_t)N_QKV * C_DIM * 2;
  bf16_t* Wpt  = (bf16_t*)ws;  ws += (size_t)C_DIM * C_DIM * 2;
  bf16_t* qkv  = (bf16_t*)ws;  ws += (size_t)M_TOK * N_QKV * 2;
  bf16_t* attn = (bf16_t*)ws;  ws += (size_t)M_TOK * C_DIM * 2;

  {
    int n4 = (M_TOK * C_DIM) / 4;
    cvt_f32_to_bf16<<<n4 / 256, 256, 0, stream>>>(x, xb, n4);
  }
  transpose_f32_to_bf16<<<dim3(N_QKV / 32, C_DIM / 32), dim3(32, 8), 0, stream>>>(W_attn, Wat, C_DIM, N_QKV);
  transpose_f32_to_bf16<<<dim3(C_DIM / 32, C_DIM / 32), dim3(32, 8), 0, stream>>>(W_proj, Wpt, C_DIM, C_DIM);

  gemm_bt_bias<<<dim3(M_TOK / BM, N_QKV / BN), 256, 0, stream>>>(
      xb, Wat, b_attn, qkv, M_TOK, N_QKV, C_DIM);

  attn_fwd<<<dim3(NT, H_DIM, B_DIM), 256, 0, stream>>>(qkv, attn);

  gemm_bt_bias_n64<<<dim3(M_TOK / BM, C_DIM / 64), 256, 0, stream>>>(
      attn, Wpt, b_proj, out, M_TOK, C_DIM, C_DIM);
}